// Round 6
// baseline (370.571 us; speedup 1.0000x reference)
//
#include <hip/hip_runtime.h>
#include <hip/hip_fp16.h>
#include <hip/hip_bf16.h>

#define NB 8
#define NC 64
#define NH 256
#define NW 512
#define ND 16
#define HW (NH * NW)          // 131072
#define EPSV 1e-6f
#define EXT 324               // 18x18 extended pixels
#define RSH 56                // LDS record stride in halves (112 B)
#define OVS 24                // ov buffer stride in halves (48 B)

typedef __attribute__((ext_vector_type(8))) short bf16x8;
typedef __attribute__((ext_vector_type(4))) float f32x4;

__device__ __forceinline__ unsigned pack_bf16rn(float aa, float bb) {
    union { __hip_bfloat162 h2; unsigned u; } c;
    c.h2 = __float22bfloat162_rn(float2{aa, bb});
    return c.u;
}
__device__ __forceinline__ float hi_part(float f) {
    return __uint_as_float(__float_as_uint(f) & 0xFFFF0000u);
}
__device__ __forceinline__ unsigned pack_hi2(float aa, float bb) {
    return (__float_as_uint(bb) & 0xFFFF0000u) | (__float_as_uint(aa) >> 16);
}
__device__ __forceinline__ float fdot2f(unsigned ua, unsigned ub, float c) {
#if __has_builtin(__builtin_amdgcn_fdot2)
    typedef __attribute__((ext_vector_type(2))) _Float16 h2t;
    union { unsigned u; h2t h; } A, B;
    A.u = ua; B.u = ub;
    return __builtin_amdgcn_fdot2(A.h, B.h, c, false);
#else
    union { unsigned u; __half2 h; } A, B;
    A.u = ua; B.u = ub;
    float2 fa = __half22float2(A.h), fb = __half22float2(B.h);
    return fmaf(fa.y, fb.y, fmaf(fa.x, fb.x, c));
#endif
}

// ---------------------------------------------------------------------------
// Fully fused NA2D, v6. Block = 512 threads (8 waves), tile = 16x16 interior.
//  Phase 1: qkv projection via MFMA (W bf16-rn, x exact hi/lo), fp16 records
//           in LDS (36.3 KB).
//  Phase 2: scores via v_dot2_f32_f16, weighted-V via v_pk_fma_f16.
//  Phase 3: output projection 16->64 via MFMA (wout hi/lo exact, ov bf16-rn),
//           ov redistributed through reused LDS. Stores from D fragments.
// ---------------------------------------------------------------------------
__global__ __launch_bounds__(512, 4)
void na2d_fused_v6(const float* __restrict__ x,
                   const float* __restrict__ wqkv,
                   const float* __restrict__ wout,
                   float* __restrict__ y)
{
    __shared__ __align__(16) __half s[EXT * RSH];   // 36288 B

    const int t    = threadIdx.x;
    const int wid  = t >> 6;
    const int lane = t & 63;
    const int lg   = lane >> 4;     // 0..3
    const int lr   = lane & 15;     // 0..15

    // XCD swizzle: each XCD owns one batch image -> halo reuse in its L2.
    const int wg = (blockIdx.x & 7) * 512 + (blockIdx.x >> 3);
    const int bx = wg & 31;
    const int by = (wg >> 5) & 15;
    const int b  = wg >> 9;
    const int w0 = bx * 16;
    const int h0 = by * 16;

    const float* __restrict__ xb = x + (size_t)b * NC * HW;

    // ---- Phase 1: qkv projection ----
    bf16x8 a[3][2];
    #pragma unroll
    for (int og = 0; og < 3; ++og) {
        const int row = og * 16 + lr;
        #pragma unroll
        for (int ks = 0; ks < 2; ++ks) {
            union { bf16x8 v; unsigned u[4]; } r;
            #pragma unroll
            for (int i = 0; i < 4; ++i)
                r.u[i] = pack_bf16rn(wqkv[row * NC + ks * 32 + lg * 8 + 2 * i],
                                     wqkv[row * NC + ks * 32 + lg * 8 + 2 * i + 1]);
            a[og][ks] = r.v;
        }
    }

    f32x4 acc[3][3];
    #pragma unroll
    for (int og = 0; og < 3; ++og)
        #pragma unroll
        for (int pg = 0; pg < 3; ++pg)
            acc[og][pg] = (f32x4)(0.f);

    const int pb = wid * 48;    // wave 7: all pad (skipped)

    #pragma unroll
    for (int pg = 0; pg < 3; ++pg) {
        if (pb + pg * 16 < EXT) {
            const int pe = pb + pg * 16 + lr;
            const int ey = pe / 18;
            const int ex = pe - ey * 18;
            int hh = h0 + ey - 1;
            int ww = w0 + ex - 1;
            hh = hh < 0 ? 0 : (hh > NH - 1 ? NH - 1 : hh);
            ww = ww < 0 ? 0 : (ww > NW - 1 ? NW - 1 : ww);
            const float* xp = xb + hh * NW + ww;

            float xv[16];
            #pragma unroll
            for (int j = 0; j < 16; ++j)
                xv[j] = xp[(size_t)((j >> 3) * 32 + lg * 8 + (j & 7)) * HW];

            union { bf16x8 v; unsigned u[4]; } bh[2], bl[2];
            #pragma unroll
            for (int ks = 0; ks < 2; ++ks)
                #pragma unroll
                for (int i = 0; i < 4; ++i) {
                    const float f0 = xv[ks * 8 + 2 * i];
                    const float f1 = xv[ks * 8 + 2 * i + 1];
                    bh[ks].u[i] = pack_hi2(f0, f1);
                    bl[ks].u[i] = pack_hi2(f0 - hi_part(f0), f1 - hi_part(f1));
                }
            #pragma unroll
            for (int og = 0; og < 3; ++og) {
                #pragma unroll
                for (int ks = 0; ks < 2; ++ks) {
                    acc[og][pg] = __builtin_amdgcn_mfma_f32_16x16x32_bf16(a[og][ks], bh[ks].v, acc[og][pg], 0, 0, 0);
                    acc[og][pg] = __builtin_amdgcn_mfma_f32_16x16x32_bf16(a[og][ks], bl[ks].v, acc[og][pg], 0, 0, 0);
                }
            }
        }
    }

    // phi on q,k; zero OOB; pack fp16 records
    #pragma unroll
    for (int pg = 0; pg < 3; ++pg) {
        const int pe = pb + pg * 16 + lr;
        if (pe < EXT) {
            const int ey = pe / 18;
            const int ex = pe - ey * 18;
            const int hh = h0 + ey - 1;
            const int ww = w0 + ex - 1;
            const bool valid = (unsigned)hh < NH && (unsigned)ww < NW;
            #pragma unroll
            for (int og = 0; og < 3; ++og) {
                f32x4 v = acc[og][pg];
                if (og < 2) {
                    #pragma unroll
                    for (int i = 0; i < 4; ++i)
                        v[i] = v[i] > 0.f ? v[i] + 1.f : __expf(v[i]);
                }
                if (!valid) v = (f32x4)(0.f);
                union { uint2 d; struct { __half2 a2, b2; } h; } pk;
                pk.h.a2 = __floats2half2_rn(v[0], v[1]);
                pk.h.b2 = __floats2half2_rn(v[2], v[3]);
                *reinterpret_cast<uint2*>(&s[pe * RSH + og * 16 + lg * 4]) = pk.d;
            }
        }
    }
    __syncthreads();

    // ---- Phase 2: attention (wave-pairs duplicate; even wave publishes) ----
    const int p  = (wid >> 1) * 64 + lane;
    const int py = p >> 4, px = p & 15;

    uint4 q0, q1;
    {
        const __half* qp = &s[((py + 1) * 18 + (px + 1)) * RSH];
        q0 = *reinterpret_cast<const uint4*>(qp);
        q1 = *reinterpret_cast<const uint4*>(qp + 8);
    }

    float sc[9];
    float ssum = 0.f;
    #pragma unroll
    for (int n = 0; n < 9; ++n) {
        const int r = (py + n / 3) * 18 + (px + n % 3);
        const __half* kp = &s[r * RSH + 16];
        const uint4 k0 = *reinterpret_cast<const uint4*>(kp);
        const uint4 k1 = *reinterpret_cast<const uint4*>(kp + 8);
        float sv = 0.f;
        sv = fdot2f(q0.x, k0.x, sv);
        sv = fdot2f(q0.y, k0.y, sv);
        sv = fdot2f(q0.z, k0.z, sv);
        sv = fdot2f(q0.w, k0.w, sv);
        sv = fdot2f(q1.x, k1.x, sv);
        sv = fdot2f(q1.y, k1.y, sv);
        sv = fdot2f(q1.z, k1.z, sv);
        sv = fdot2f(q1.w, k1.w, sv);
        sc[n] = sv;
        ssum += sv;
    }
    const float inv = 1.f / (ssum + EPSV);

    __half2 ovh[8];
    #pragma unroll
    for (int i = 0; i < 8; ++i) ovh[i] = __half2half2(__float2half_rn(0.f));
    #pragma unroll
    for (int n = 0; n < 9; ++n) {
        const int r = (py + n / 3) * 18 + (px + n % 3);
        const __half* vp = &s[r * RSH + 32];
        union { uint4 u; __half2 h[4]; } v0, v1;
        v0.u = *reinterpret_cast<const uint4*>(vp);
        v1.u = *reinterpret_cast<const uint4*>(vp + 8);
        const __half2 wn2 = __half2half2(__float2half_rn(sc[n] * inv));
        #pragma unroll
        for (int i = 0; i < 4; ++i) ovh[i]     = __hfma2(wn2, v0.h[i], ovh[i]);
        #pragma unroll
        for (int i = 0; i < 4; ++i) ovh[4 + i] = __hfma2(wn2, v1.h[i], ovh[4 + i]);
    }

    // A-fragments for out-projection: wout exact hi/lo split, K padded 16->32
    bf16x8 oahi[4], oalo[4];
    #pragma unroll
    for (int c = 0; c < 4; ++c) {
        const int row = c * 16 + lr;
        union { bf16x8 v; unsigned u[4]; } rh, rl;
        #pragma unroll
        for (int i2 = 0; i2 < 4; ++i2) {
            const int k0i = lg * 8 + 2 * i2;
            const float f0 = k0i < 16     ? wout[row * ND + k0i]     : 0.f;
            const float f1 = k0i + 1 < 16 ? wout[row * ND + k0i + 1] : 0.f;
            rh.u[i2] = pack_hi2(f0, f1);
            rl.u[i2] = pack_hi2(f0 - hi_part(f0), f1 - hi_part(f1));
        }
        oahi[c] = rh.v;
        oalo[c] = rl.v;
    }

    __syncthreads();   // all record reads complete

    // publish ov as bf16 into reused LDS (even waves only)
    __half* ovb = s;
    if (!(wid & 1)) {
        unsigned ub[8];
        #pragma unroll
        for (int i = 0; i < 8; ++i) {
            const float2 f = __half22float2(ovh[i]);
            ub[i] = pack_bf16rn(f.x, f.y);
        }
        uint4* d = reinterpret_cast<uint4*>(&ovb[p * OVS]);
        d[0] = make_uint4(ub[0], ub[1], ub[2], ub[3]);
        d[1] = make_uint4(ub[4], ub[5], ub[6], ub[7]);
    }
    __syncthreads();

    // ---- Phase 3: MFMA out-projection; wave owns pixel-rows 2*wid, 2*wid+1
    #pragma unroll
    for (int g2 = 0; g2 < 2; ++g2) {
        const int g = wid * 2 + g2;          // tile row 0..15
        bf16x8 bf = (bf16x8)(short)0;
        if (lg < 2)
            bf = *reinterpret_cast<const bf16x8*>(&ovb[(g * 16 + lr) * OVS + lg * 8]);
        f32x4 D[4];
        #pragma unroll
        for (int c = 0; c < 4; ++c) {
            D[c] = (f32x4)(0.f);
            D[c] = __builtin_amdgcn_mfma_f32_16x16x32_bf16(oahi[c], bf, D[c], 0, 0, 0);
            D[c] = __builtin_amdgcn_mfma_f32_16x16x32_bf16(oalo[c], bf, D[c], 0, 0, 0);
        }
        float* yp = y + (size_t)b * NC * HW + (size_t)(h0 + g) * NW + w0 + lr;
        #pragma unroll
        for (int c = 0; c < 4; ++c)
            #pragma unroll
            for (int i = 0; i < 4; ++i)
                yp[(size_t)(c * 16 + lg * 4 + i) * HW] = D[c][i];
    }
}

extern "C" void kernel_launch(void* const* d_in, const int* in_sizes, int n_in,
                              void* d_out, int out_size, void* d_ws, size_t ws_size,
                              hipStream_t stream)
{
    const float* x    = (const float*)d_in[0];
    const float* wqkv = (const float*)d_in[1];
    const float* wout = (const float*)d_in[2];
    float* y = (float*)d_out;

    const int nblocks = (NW / 16) * (NH / 16) * NB;   // 4096
    na2d_fused_v6<<<nblocks, 512, 0, stream>>>(x, wqkv, wout, y);
}

// Round 7
// 247.780 us; speedup vs baseline: 1.4956x; 1.4956x over previous
//
#include <hip/hip_runtime.h>
#include <hip/hip_fp16.h>
#include <hip/hip_bf16.h>

#define NB 8
#define NC 64
#define NH 256
#define NW 512
#define ND 16
#define HW (NH * NW)          // 131072
#define EPSV 1e-6f
#define EXT 324               // 18x18 extended pixels
#define RSH 56                // LDS record stride in halves (112 B)
#define OVS 24                // ov buffer stride in halves (48 B)

typedef __attribute__((ext_vector_type(8))) short bf16x8;
typedef __attribute__((ext_vector_type(4))) float f32x4;

__device__ __forceinline__ unsigned pack_bf16rn(float aa, float bb) {
    union { __hip_bfloat162 h2; unsigned u; } c;
    c.h2 = __float22bfloat162_rn(float2{aa, bb});
    return c.u;
}
__device__ __forceinline__ float hi_part(float f) {
    return __uint_as_float(__float_as_uint(f) & 0xFFFF0000u);
}
__device__ __forceinline__ unsigned pack_hi2(float aa, float bb) {
    return (__float_as_uint(bb) & 0xFFFF0000u) | (__float_as_uint(aa) >> 16);
}
__device__ __forceinline__ float fdot2f(unsigned ua, unsigned ub, float c) {
#if __has_builtin(__builtin_amdgcn_fdot2)
    typedef __attribute__((ext_vector_type(2))) _Float16 h2t;
    union { unsigned u; h2t h; } A, B;
    A.u = ua; B.u = ub;
    return __builtin_amdgcn_fdot2(A.h, B.h, c, false);
#else
    union { unsigned u; __half2 h; } A, B;
    A.u = ua; B.u = ub;
    float2 fa = __half22float2(A.h), fb = __half22float2(B.h);
    return fmaf(fa.y, fb.y, fmaf(fa.x, fb.x, c));
#endif
}

// ---------------------------------------------------------------------------
// Fully fused NA2D, v7. Block = 512 threads (8 waves), tile = 16x16 interior.
//  Phase 1: qkv projection via MFMA (W bf16-rn, x exact hi/lo), fp16 records
//           in LDS (36.3 KB).
//  Phase 2: scores via v_dot2_f32_f16, weighted-V via v_pk_fma_f16; even
//           waves publish ov (bf16) to a SEPARATE LDS region (12.3 KB).
//  Phase 3: after barrier: load wout fragments, MFMA out-projection, store.
//  Liveness across barriers kept minimal (v6 spilled ~32 regs to scratch:
//  WRITE_SIZE 287->802 MB; this version computes phase-3 state after sync).
// ---------------------------------------------------------------------------
__global__ __launch_bounds__(512, 4)
void na2d_fused_v7(const float* __restrict__ x,
                   const float* __restrict__ wqkv,
                   const float* __restrict__ wout,
                   float* __restrict__ y)
{
    __shared__ __align__(16) __half s[EXT * RSH];     // 36288 B
    __shared__ __align__(16) __half ovb[256 * OVS];   // 12288 B

    const int t    = threadIdx.x;
    const int wid  = t >> 6;
    const int lane = t & 63;
    const int lg   = lane >> 4;     // 0..3
    const int lr   = lane & 15;     // 0..15

    // XCD swizzle: each XCD owns one batch image -> halo reuse in its L2.
    const int wg = (blockIdx.x & 7) * 512 + (blockIdx.x >> 3);
    const int bx = wg & 31;
    const int by = (wg >> 5) & 15;
    const int b  = wg >> 9;
    const int w0 = bx * 16;
    const int h0 = by * 16;

    const float* __restrict__ xb = x + (size_t)b * NC * HW;

    // ---- Phase 1: qkv projection ----
    {
        bf16x8 a[3][2];
        #pragma unroll
        for (int og = 0; og < 3; ++og) {
            const int row = og * 16 + lr;
            #pragma unroll
            for (int ks = 0; ks < 2; ++ks) {
                union { bf16x8 v; unsigned u[4]; } r;
                #pragma unroll
                for (int i = 0; i < 4; ++i)
                    r.u[i] = pack_bf16rn(wqkv[row * NC + ks * 32 + lg * 8 + 2 * i],
                                         wqkv[row * NC + ks * 32 + lg * 8 + 2 * i + 1]);
                a[og][ks] = r.v;
            }
        }

        f32x4 acc[3][3];
        #pragma unroll
        for (int og = 0; og < 3; ++og)
            #pragma unroll
            for (int pg = 0; pg < 3; ++pg)
                acc[og][pg] = (f32x4)(0.f);

        const int pb = wid * 48;    // wave 7: all pad (skipped)

        #pragma unroll
        for (int pg = 0; pg < 3; ++pg) {
            if (pb + pg * 16 < EXT) {
                const int pe = pb + pg * 16 + lr;
                const int ey = pe / 18;
                const int ex = pe - ey * 18;
                int hh = h0 + ey - 1;
                int ww = w0 + ex - 1;
                hh = hh < 0 ? 0 : (hh > NH - 1 ? NH - 1 : hh);
                ww = ww < 0 ? 0 : (ww > NW - 1 ? NW - 1 : ww);
                const float* xp = xb + hh * NW + ww;

                float xv[16];
                #pragma unroll
                for (int j = 0; j < 16; ++j)
                    xv[j] = xp[(size_t)((j >> 3) * 32 + lg * 8 + (j & 7)) * HW];

                union { bf16x8 v; unsigned u[4]; } bh[2], bl[2];
                #pragma unroll
                for (int ks = 0; ks < 2; ++ks)
                    #pragma unroll
                    for (int i = 0; i < 4; ++i) {
                        const float f0 = xv[ks * 8 + 2 * i];
                        const float f1 = xv[ks * 8 + 2 * i + 1];
                        bh[ks].u[i] = pack_hi2(f0, f1);
                        bl[ks].u[i] = pack_hi2(f0 - hi_part(f0), f1 - hi_part(f1));
                    }
                #pragma unroll
                for (int og = 0; og < 3; ++og) {
                    #pragma unroll
                    for (int ks = 0; ks < 2; ++ks) {
                        acc[og][pg] = __builtin_amdgcn_mfma_f32_16x16x32_bf16(a[og][ks], bh[ks].v, acc[og][pg], 0, 0, 0);
                        acc[og][pg] = __builtin_amdgcn_mfma_f32_16x16x32_bf16(a[og][ks], bl[ks].v, acc[og][pg], 0, 0, 0);
                    }
                }
            }
        }

        // phi on q,k; zero OOB; pack fp16 records
        #pragma unroll
        for (int pg = 0; pg < 3; ++pg) {
            const int pe = pb + pg * 16 + lr;
            if (pe < EXT) {
                const int ey = pe / 18;
                const int ex = pe - ey * 18;
                const int hh = h0 + ey - 1;
                const int ww = w0 + ex - 1;
                const bool valid = (unsigned)hh < NH && (unsigned)ww < NW;
                #pragma unroll
                for (int og = 0; og < 3; ++og) {
                    f32x4 v = acc[og][pg];
                    if (og < 2) {
                        #pragma unroll
                        for (int i = 0; i < 4; ++i)
                            v[i] = v[i] > 0.f ? v[i] + 1.f : __expf(v[i]);
                    }
                    if (!valid) v = (f32x4)(0.f);
                    union { uint2 d; struct { __half2 a2, b2; } h; } pk;
                    pk.h.a2 = __floats2half2_rn(v[0], v[1]);
                    pk.h.b2 = __floats2half2_rn(v[2], v[3]);
                    *reinterpret_cast<uint2*>(&s[pe * RSH + og * 16 + lg * 4]) = pk.d;
                }
            }
        }
    }
    __syncthreads();

    // ---- Phase 2: attention (wave-pairs duplicate; even wave publishes) ----
    {
        const int p  = (wid >> 1) * 64 + lane;
        const int py = p >> 4, px = p & 15;

        uint4 q0, q1;
        {
            const __half* qp = &s[((py + 1) * 18 + (px + 1)) * RSH];
            q0 = *reinterpret_cast<const uint4*>(qp);
            q1 = *reinterpret_cast<const uint4*>(qp + 8);
        }

        float sc[9];
        float ssum = 0.f;
        #pragma unroll
        for (int n = 0; n < 9; ++n) {
            const int r = (py + n / 3) * 18 + (px + n % 3);
            const __half* kp = &s[r * RSH + 16];
            const uint4 k0 = *reinterpret_cast<const uint4*>(kp);
            const uint4 k1 = *reinterpret_cast<const uint4*>(kp + 8);
            float sv = 0.f;
            sv = fdot2f(q0.x, k0.x, sv);
            sv = fdot2f(q0.y, k0.y, sv);
            sv = fdot2f(q0.z, k0.z, sv);
            sv = fdot2f(q0.w, k0.w, sv);
            sv = fdot2f(q1.x, k1.x, sv);
            sv = fdot2f(q1.y, k1.y, sv);
            sv = fdot2f(q1.z, k1.z, sv);
            sv = fdot2f(q1.w, k1.w, sv);
            sc[n] = sv;
            ssum += sv;
        }
        const float inv = 1.f / (ssum + EPSV);

        __half2 ovh[8];
        #pragma unroll
        for (int i = 0; i < 8; ++i) ovh[i] = __half2half2(__float2half_rn(0.f));
        #pragma unroll
        for (int n = 0; n < 9; ++n) {
            const int r = (py + n / 3) * 18 + (px + n % 3);
            const __half* vp = &s[r * RSH + 32];
            union { uint4 u; __half2 h[4]; } v0, v1;
            v0.u = *reinterpret_cast<const uint4*>(vp);
            v1.u = *reinterpret_cast<const uint4*>(vp + 8);
            const __half2 wn2 = __half2half2(__float2half_rn(sc[n] * inv));
            #pragma unroll
            for (int i = 0; i < 4; ++i) ovh[i]     = __hfma2(wn2, v0.h[i], ovh[i]);
            #pragma unroll
            for (int i = 0; i < 4; ++i) ovh[4 + i] = __hfma2(wn2, v1.h[i], ovh[4 + i]);
        }

        // publish ov (bf16) to separate LDS region (even waves only)
        if (!(wid & 1)) {
            unsigned ub[8];
            #pragma unroll
            for (int i = 0; i < 8; ++i) {
                const float2 f = __half22float2(ovh[i]);
                ub[i] = pack_bf16rn(f.x, f.y);
            }
            uint4* d = reinterpret_cast<uint4*>(&ovb[p * OVS]);
            d[0] = make_uint4(ub[0], ub[1], ub[2], ub[3]);
            d[1] = make_uint4(ub[4], ub[5], ub[6], ub[7]);
        }
    }
    __syncthreads();

    // ---- Phase 3: MFMA out-projection (fragments loaded AFTER barrier) ----
    {
        bf16x8 oahi[4], oalo[4];
        #pragma unroll
        for (int c = 0; c < 4; ++c) {
            const int row = c * 16 + lr;
            union { bf16x8 v; unsigned u[4]; } rh, rl;
            #pragma unroll
            for (int i2 = 0; i2 < 4; ++i2) {
                const int k0i = lg * 8 + 2 * i2;
                const float f0 = k0i < 16     ? wout[row * ND + k0i]     : 0.f;
                const float f1 = k0i + 1 < 16 ? wout[row * ND + k0i + 1] : 0.f;
                rh.u[i2] = pack_hi2(f0, f1);
                rl.u[i2] = pack_hi2(f0 - hi_part(f0), f1 - hi_part(f1));
            }
            oahi[c] = rh.v;
            oalo[c] = rl.v;
        }

        #pragma unroll
        for (int g2 = 0; g2 < 2; ++g2) {
            const int g = wid * 2 + g2;          // tile row 0..15
            bf16x8 bf = (bf16x8)(short)0;
            if (lg < 2)
                bf = *reinterpret_cast<const bf16x8*>(&ovb[(g * 16 + lr) * OVS + lg * 8]);
            f32x4 D[4];
            #pragma unroll
            for (int c = 0; c < 4; ++c) {
                D[c] = (f32x4)(0.f);
                D[c] = __builtin_amdgcn_mfma_f32_16x16x32_bf16(oahi[c], bf, D[c], 0, 0, 0);
                D[c] = __builtin_amdgcn_mfma_f32_16x16x32_bf16(oalo[c], bf, D[c], 0, 0, 0);
            }
            float* yp = y + (size_t)b * NC * HW + (size_t)(h0 + g) * NW + w0 + lr;
            #pragma unroll
            for (int c = 0; c < 4; ++c)
                #pragma unroll
                for (int i = 0; i < 4; ++i)
                    yp[(size_t)(c * 16 + lg * 4 + i) * HW] = D[c][i];
        }
    }
}

extern "C" void kernel_launch(void* const* d_in, const int* in_sizes, int n_in,
                              void* d_out, int out_size, void* d_ws, size_t ws_size,
                              hipStream_t stream)
{
    const float* x    = (const float*)d_in[0];
    const float* wqkv = (const float*)d_in[1];
    const float* wout = (const float*)d_in[2];
    float* y = (float*)d_out;

    const int nblocks = (NW / 16) * (NH / 16) * NB;   // 4096
    na2d_fused_v7<<<nblocks, 512, 0, stream>>>(x, wqkv, wout, y);
}

// Round 8
// 212.631 us; speedup vs baseline: 1.7428x; 1.1653x over previous
//
#include <hip/hip_runtime.h>
#include <hip/hip_fp16.h>
#include <hip/hip_bf16.h>

#define NB 8
#define NC 64
#define NH 256
#define NW 512
#define ND 16
#define HW (NH * NW)          // 131072
#define EPSV 1e-6f
#define EXT 324               // 18x18 extended pixels
#define RSH 56                // LDS record stride in halves (112 B)

typedef __attribute__((ext_vector_type(8))) short bf16x8;
typedef __attribute__((ext_vector_type(4))) float f32x4;

__device__ __forceinline__ unsigned pack_bf16rn(float aa, float bb) {
    union { __hip_bfloat162 h2; unsigned u; } c;
    c.h2 = __float22bfloat162_rn(float2{aa, bb});
    return c.u;
}
__device__ __forceinline__ float hi_part(float f) {
    return __uint_as_float(__float_as_uint(f) & 0xFFFF0000u);
}
__device__ __forceinline__ unsigned pack_hi2(float aa, float bb) {
    return (__float_as_uint(bb) & 0xFFFF0000u) | (__float_as_uint(aa) >> 16);
}
__device__ __forceinline__ float fdot2f(unsigned ua, unsigned ub, float c) {
#if __has_builtin(__builtin_amdgcn_fdot2)
    typedef __attribute__((ext_vector_type(2))) _Float16 h2t;
    union { unsigned u; h2t h; } A, B;
    A.u = ua; B.u = ub;
    return __builtin_amdgcn_fdot2(A.h, B.h, c, false);
#else
    union { unsigned u; __half2 h; } A, B;
    A.u = ua; B.u = ub;
    float2 fa = __half22float2(A.h), fb = __half22float2(B.h);
    return fmaf(fa.y, fb.y, fmaf(fa.x, fb.x, c));
#endif
}

// ---------------------------------------------------------------------------
// Fully fused NA2D, v8 = v5 (fastest so far) + hoisted phase-1 loads.
//  Phase 1: all 48 x-loads per thread issued into DISTINCT registers
//           (xv[3][16], fully unrolled -> no scratch) before any consumption:
//           one latency wait instead of three serialized batches.
//           qkv projection via MFMA (W bf16-rn, x exact hi/lo); per-pg
//           acc/phi/record-store merged so accumulators die early.
//  Phase 2: scores via v_dot2_f32_f16, weighted-V via v_pk_fma_f16
//           (wave-pairs duplicate; channel-half split by wave parity).
//  Phase 3: scalar out-projection 16->64 (wout rows wave-uniform -> s_load).
//  Single barrier total.
// ---------------------------------------------------------------------------
__global__ __launch_bounds__(512, 4)
void na2d_fused_v8(const float* __restrict__ x,
                   const float* __restrict__ wqkv,
                   const float* __restrict__ wout,
                   float* __restrict__ y)
{
    __shared__ __align__(16) __half s[EXT * RSH];   // 36288 B

    const int t    = threadIdx.x;
    const int wid  = t >> 6;
    const int lane = t & 63;
    const int lg   = lane >> 4;     // 0..3
    const int lr   = lane & 15;     // 0..15

    // XCD swizzle: each XCD owns one batch image -> halo reuse in its L2.
    const int wg = (blockIdx.x & 7) * 512 + (blockIdx.x >> 3);
    const int bx = wg & 31;
    const int by = (wg >> 5) & 15;
    const int b  = wg >> 9;
    const int w0 = bx * 16;
    const int h0 = by * 16;

    const float* __restrict__ xb = x + (size_t)b * NC * HW;

    // ---- Phase 1a: issue ALL long-latency loads up front ----
    const int pb = wid * 48;        // wave 7: pb=336 -> all pg skipped

    float xv[3][16];                // fully unrolled static indexing -> VGPRs
    #pragma unroll
    for (int pg = 0; pg < 3; ++pg) {
        if (pb + pg * 16 < EXT) {                  // wave-uniform
            const int pe = pb + pg * 16 + lr;
            const int ey = pe / 18;
            const int ex = pe - ey * 18;
            int hh = h0 + ey - 1;
            int ww = w0 + ex - 1;
            hh = hh < 0 ? 0 : (hh > NH - 1 ? NH - 1 : hh);   // clamp: safe addr,
            ww = ww < 0 ? 0 : (ww > NW - 1 ? NW - 1 : ww);   // zeroed at store
            const float* xp = xb + hh * NW + ww;
            #pragma unroll
            for (int j = 0; j < 16; ++j)
                xv[pg][j] = xp[(size_t)((j >> 3) * 32 + lg * 8 + (j & 7)) * HW];
        }
    }

    // A fragments: wqkv rows, single rounded bf16 (24 VGPR)
    bf16x8 a[3][2];
    #pragma unroll
    for (int og = 0; og < 3; ++og) {
        const int row = og * 16 + lr;
        #pragma unroll
        for (int ks = 0; ks < 2; ++ks) {
            union { bf16x8 v; unsigned u[4]; } r;
            #pragma unroll
            for (int i = 0; i < 4; ++i)
                r.u[i] = pack_bf16rn(wqkv[row * NC + ks * 32 + lg * 8 + 2 * i],
                                     wqkv[row * NC + ks * 32 + lg * 8 + 2 * i + 1]);
            a[og][ks] = r.v;
        }
    }

    // ---- Phase 1b: per-pg pack -> MFMA -> phi -> LDS record store ----
    #pragma unroll
    for (int pg = 0; pg < 3; ++pg) {
        if (pb + pg * 16 < EXT) {                  // wave-uniform
            const int pe = pb + pg * 16 + lr;
            const int ey = pe / 18;
            const int ex = pe - ey * 18;
            const int hh = h0 + ey - 1;
            const int ww = w0 + ex - 1;
            const bool valid = (unsigned)hh < NH && (unsigned)ww < NW;

            union { bf16x8 v; unsigned u[4]; } bh[2], bl[2];
            #pragma unroll
            for (int ks = 0; ks < 2; ++ks)
                #pragma unroll
                for (int i = 0; i < 4; ++i) {
                    const float f0 = xv[pg][ks * 8 + 2 * i];
                    const float f1 = xv[pg][ks * 8 + 2 * i + 1];
                    bh[ks].u[i] = pack_hi2(f0, f1);
                    bl[ks].u[i] = pack_hi2(f0 - hi_part(f0), f1 - hi_part(f1));
                }

            f32x4 acc[3];
            #pragma unroll
            for (int og = 0; og < 3; ++og) {
                acc[og] = (f32x4)(0.f);
                #pragma unroll
                for (int ks = 0; ks < 2; ++ks) {
                    acc[og] = __builtin_amdgcn_mfma_f32_16x16x32_bf16(a[og][ks], bh[ks].v, acc[og], 0, 0, 0);
                    acc[og] = __builtin_amdgcn_mfma_f32_16x16x32_bf16(a[og][ks], bl[ks].v, acc[og], 0, 0, 0);
                }
            }

            if (pe < EXT) {                        // per-lane (wave 6 tail)
                #pragma unroll
                for (int og = 0; og < 3; ++og) {
                    f32x4 v = acc[og];
                    if (og < 2) {                  // phi = elu + 1 on q,k
                        #pragma unroll
                        for (int i = 0; i < 4; ++i)
                            v[i] = v[i] > 0.f ? v[i] + 1.f : __expf(v[i]);
                    }
                    if (!valid) v = (f32x4)(0.f);  // zero-pad AFTER phi
                    union { uint2 d; struct { __half2 a2, b2; } h; } pk;
                    pk.h.a2 = __floats2half2_rn(v[0], v[1]);
                    pk.h.b2 = __floats2half2_rn(v[2], v[3]);
                    *reinterpret_cast<uint2*>(&s[pe * RSH + og * 16 + lg * 4]) = pk.d;
                }
            }
        }
    }
    __syncthreads();

    // ---- Phase 2: attention (wave-pairs duplicate; chalf by parity) ----
    const int p  = (wid >> 1) * 64 + lane;
    const int py = p >> 4, px = p & 15;

    uint4 q0, q1;
    {
        const __half* qp = &s[((py + 1) * 18 + (px + 1)) * RSH];
        q0 = *reinterpret_cast<const uint4*>(qp);
        q1 = *reinterpret_cast<const uint4*>(qp + 8);
    }

    float sc[9];
    float ssum = 0.f;
    #pragma unroll
    for (int n = 0; n < 9; ++n) {
        const int r = (py + n / 3) * 18 + (px + n % 3);
        const __half* kp = &s[r * RSH + 16];
        const uint4 k0 = *reinterpret_cast<const uint4*>(kp);
        const uint4 k1 = *reinterpret_cast<const uint4*>(kp + 8);
        float sv = 0.f;
        sv = fdot2f(q0.x, k0.x, sv);
        sv = fdot2f(q0.y, k0.y, sv);
        sv = fdot2f(q0.z, k0.z, sv);
        sv = fdot2f(q0.w, k0.w, sv);
        sv = fdot2f(q1.x, k1.x, sv);
        sv = fdot2f(q1.y, k1.y, sv);
        sv = fdot2f(q1.z, k1.z, sv);
        sv = fdot2f(q1.w, k1.w, sv);
        sc[n] = sv;
        ssum += sv;
    }
    const float inv = 1.f / (ssum + EPSV);

    __half2 ovh[8];
    #pragma unroll
    for (int i = 0; i < 8; ++i) ovh[i] = __half2half2(__float2half_rn(0.f));
    #pragma unroll
    for (int n = 0; n < 9; ++n) {
        const int r = (py + n / 3) * 18 + (px + n % 3);
        const __half* vp = &s[r * RSH + 32];
        union { uint4 u; __half2 h[4]; } v0, v1;
        v0.u = *reinterpret_cast<const uint4*>(vp);
        v1.u = *reinterpret_cast<const uint4*>(vp + 8);
        const __half2 wn2 = __half2half2(__float2half_rn(sc[n] * inv));
        #pragma unroll
        for (int i = 0; i < 4; ++i) ovh[i]     = __hfma2(wn2, v0.h[i], ovh[i]);
        #pragma unroll
        for (int i = 0; i < 4; ++i) ovh[4 + i] = __hfma2(wn2, v1.h[i], ovh[4 + i]);
    }

    // ---- Phase 3: scalar out-projection (32 channels per wave parity) ----
    float ov[ND];
    #pragma unroll
    for (int i = 0; i < 8; ++i) {
        const float2 f = __half22float2(ovh[i]);
        ov[2 * i]     = f.x;
        ov[2 * i + 1] = f.y;
    }

    const int chalf = __builtin_amdgcn_readfirstlane(wid & 1);
    const int h = h0 + py, w = w0 + px;
    float* yp = y + (size_t)b * NC * HW + (size_t)(chalf * 32) * HW + h * NW + w;
    const float* wo = wout + (chalf * 32) * ND;
    #pragma unroll 8
    for (int o = 0; o < 32; ++o) {
        float a2 = 0.f;
        #pragma unroll
        for (int d = 0; d < ND; ++d)
            a2 = fmaf(wo[o * ND + d], ov[d], a2);
        yp[(size_t)o * HW] = a2;
    }
}

extern "C" void kernel_launch(void* const* d_in, const int* in_sizes, int n_in,
                              void* d_out, int out_size, void* d_ws, size_t ws_size,
                              hipStream_t stream)
{
    const float* x    = (const float*)d_in[0];
    const float* wqkv = (const float*)d_in[1];
    const float* wout = (const float*)d_in[2];
    float* y = (float*)d_out;

    const int nblocks = (NW / 16) * (NH / 16) * NB;   // 4096
    na2d_fused_v8<<<nblocks, 512, 0, stream>>>(x, wqkv, wout, y);
}